// Round 1
// 431.553 us; speedup vs baseline: 1.0243x; 1.0243x over previous
//
#include <hip/hip_runtime.h>
#include <hip/hip_bf16.h>

typedef unsigned short u16;
typedef unsigned int u32;
typedef long long i64;
typedef __attribute__((ext_vector_type(8))) short s8v;    // 8 bf16 (4 VGPRs)
typedef __attribute__((ext_vector_type(4))) float f32x4;  // MFMA acc

__device__ __forceinline__ float bf2f(u16 u) {
    union { u32 i; float f; } x; x.i = ((u32)u) << 16; return x.f;
}
__device__ __forceinline__ u16 f2bf(float f) {
    union { float f; u32 i; } x; x.f = f;
    u32 v = x.i;
    u32 r = v + 0x7FFFu + ((v >> 16) & 1u);   // RNE
    return (u16)(r >> 16);
}
__device__ __forceinline__ float get_f(const void* p, size_t i, int fp32) {
    return fp32 ? ((const float*)p)[i] : bf2f(((const u16*)p)[i]);
}
__device__ __forceinline__ int get_i(const void* p, size_t i, int m64) {
    return m64 ? (int)((const i64*)p)[i] : ((const int*)p)[i];
}
__device__ __forceinline__ float lrelu_clamp(float v) {
    v = v > 0.f ? v : 0.2f * v;
    return fminf(v, 80.f);
}

// ---------------------------------------------------------------------------
// k_init: block 0 = dtype detect; blocks 1..64 = W transpose (bf16 path);
// all blocks stride-zero cnt[]. Replaces 3 dispatches (detect, wt, memset).
// ---------------------------------------------------------------------------
__global__ __launch_bounds__(256) void k_init(
    const u16* __restrict__ hin, const int* __restrict__ eidx, int* __restrict__ flags,
    const u16* __restrict__ W, u16* __restrict__ Wt, int* __restrict__ cnt, int n_nodes)
{
    const int b = blockIdx.x, t = threadIdx.x;
    if (b == 0) {
        __shared__ int c1, c2;
        if (t == 0) { c1 = 0; c2 = 0; }
        __syncthreads();
        int l1 = 0, l2 = 0;
        for (int i = t; i < 8192; i += 256) {
            float v = bf2f(hin[i]);
            if (!(fabsf(v) <= 100.f)) l1++;
            if ((i & 1) && eidx[i] == 0) l2++;
        }
        atomicAdd(&c1, l1); atomicAdd(&c2, l2);
        __syncthreads();
        if (t == 0) {
            flags[0] = (c1 > 40) ? 1 : 0;
            flags[1] = (c2 > 3000) ? 1 : 0;
        }
    } else {
        // Wt[n][k] = W[k][n] (garbage in fp32 mode; never read there).
        int i = (b - 1) * 256 + t;
        int k = i >> 7, n = i & 127;
        Wt[(size_t)n * 128 + k] = W[(size_t)k * 128 + n];
    }
    for (int i = b * 256 + t; i < n_nodes; i += gridDim.x * 256) cnt[i] = 0;
}

// ---------------------------------------------------------------------------
// MFMA projection (bf16 mode): hp (PERMUTED: hp[row*128 + col*8 + ct] =
// h_proj[row][ct*16+col]) + fused score tables ssrc/stgt [N][4].
// Wave = 16 rows x 128 cols; A[m=lane&15][k=quad*8+j]; C/D col=lane&15,
// row=quad*4+reg. Permuted store = one 16B store per row per lane.
// ---------------------------------------------------------------------------
__global__ __launch_bounds__(256) void k_proj_mfma(
    const u16* __restrict__ hin, const u16* __restrict__ Wt,
    const u16* __restrict__ bias, const u16* __restrict__ a_src,
    const u16* __restrict__ a_tgt, const int* __restrict__ flags,
    u16* __restrict__ hp, float* __restrict__ ssrc, float* __restrict__ stgt,
    int M)
{
    if (flags[0]) return;   // fp32 handled by vector kernel
    const int wave = threadIdx.x >> 6;
    const int lane = threadIdx.x & 63;
    const int q = lane >> 4, col = lane & 15;
    const int row0 = blockIdx.x * 64 + wave * 16;
    if (row0 >= M) return;

    const int arow = min(row0 + col, M - 1);
    f32x4 acc[8];
    #pragma unroll
    for (int ct = 0; ct < 8; ct++) acc[ct] = (f32x4){0.f, 0.f, 0.f, 0.f};

    #pragma unroll
    for (int kc = 0; kc < 4; kc++) {
        s8v afrag = *(const s8v*)(hin + (size_t)arow * 128 + kc * 32 + q * 8);
        #pragma unroll
        for (int ct = 0; ct < 8; ct++) {
            s8v bfrag = *(const s8v*)(Wt + (size_t)(ct * 16 + col) * 128 + kc * 32 + q * 8);
            acc[ct] = __builtin_amdgcn_mfma_f32_16x16x32_bf16(afrag, bfrag, acc[ct], 0, 0, 0);
        }
    }

    float bb[8], as[8], at[8];
    #pragma unroll
    for (int ct = 0; ct < 8; ct++) {
        int c = ct * 16 + col;
        bb[ct] = bf2f(bias[c]);
        as[ct] = bf2f(a_src[c]);
        at[ct] = bf2f(a_tgt[c]);
    }

    #pragma unroll
    for (int r = 0; r < 4; r++) {
        int row = row0 + q * 4 + r;
        float ps0 = 0.f, ps1 = 0.f, ps2 = 0.f, ps3 = 0.f;
        float pt0 = 0.f, pt1 = 0.f, pt2 = 0.f, pt3 = 0.f;
        float ov[8];
        #pragma unroll
        for (int ct = 0; ct < 8; ct++) {
            float v = acc[ct][r] + bb[ct];
            ov[ct] = v;
            float s = v * as[ct], t2 = v * at[ct];
            if (ct < 2)      { ps0 += s; pt0 += t2; }
            else if (ct < 4) { ps1 += s; pt1 += t2; }
            else if (ct < 6) { ps2 += s; pt2 += t2; }
            else             { ps3 += s; pt3 += t2; }
        }
        if (row < M) {
            union { ushort4 h[2]; uint4 qv; } pk;
            pk.h[0] = make_ushort4(f2bf(ov[0]), f2bf(ov[1]), f2bf(ov[2]), f2bf(ov[3]));
            pk.h[1] = make_ushort4(f2bf(ov[4]), f2bf(ov[5]), f2bf(ov[6]), f2bf(ov[7]));
            *(uint4*)(hp + (size_t)row * 128 + col * 8) = pk.qv;
        }
        #pragma unroll
        for (int m = 1; m < 16; m <<= 1) {
            ps0 += __shfl_xor(ps0, m); ps1 += __shfl_xor(ps1, m);
            ps2 += __shfl_xor(ps2, m); ps3 += __shfl_xor(ps3, m);
            pt0 += __shfl_xor(pt0, m); pt1 += __shfl_xor(pt1, m);
            pt2 += __shfl_xor(pt2, m); pt3 += __shfl_xor(pt3, m);
        }
        if (row < M && col < 4) {
            float vs = col == 0 ? ps0 : col == 1 ? ps1 : col == 2 ? ps2 : ps3;
            float vt = col == 0 ? pt0 : col == 1 ? pt1 : col == 2 ? pt2 : pt3;
            ssrc[(size_t)row * 4 + col] = vs;
            stgt[(size_t)row * 4 + col] = vt;
        }
    }
}

// ---------------------------------------------------------------------------
// Vector projection (fp32 mode fallback) + fused scores. hp UN-permuted fp32.
// ---------------------------------------------------------------------------
__global__ __launch_bounds__(256) void k_proj_f32(
    const float* __restrict__ hin, const float* __restrict__ W,
    const float* __restrict__ bias, const float* __restrict__ a_src,
    const float* __restrict__ a_tgt, const int* __restrict__ flags,
    float* __restrict__ hp, float* __restrict__ ssrc, float* __restrict__ stgt,
    int n_nodes)
{
    if (!flags[0]) return;
    __shared__ float hs[32][128];
    __shared__ float sh_s[32][4], sh_t[32][4];
    const int t = threadIdx.x;
    const int row0 = blockIdx.x * 32;

    for (int i = t; i < 32 * 64; i += 256) {
        int r = i >> 6, kk = (i & 63) * 2;
        int row = row0 + r;
        float2 v = (row < n_nodes) ? *(const float2*)(hin + (size_t)row * 128 + kk)
                                   : make_float2(0.f, 0.f);
        hs[r][kk] = v.x; hs[r][kk + 1] = v.y;
    }
    __syncthreads();

    const int cg = (t & 31) * 4;
    const int rg = (t >> 5) * 4;
    float acc[4][4] = {};
    for (int k = 0; k < 128; k += 4) {
        float4 h0 = *(const float4*)&hs[rg + 0][k];
        float4 h1 = *(const float4*)&hs[rg + 1][k];
        float4 h2 = *(const float4*)&hs[rg + 2][k];
        float4 h3 = *(const float4*)&hs[rg + 3][k];
        #pragma unroll
        for (int j = 0; j < 4; j++) {
            float4 w4 = *(const float4*)(W + (size_t)(k + j) * 128 + cg);
            float hh0 = ((const float*)&h0)[j], hh1 = ((const float*)&h1)[j];
            float hh2 = ((const float*)&h2)[j], hh3 = ((const float*)&h3)[j];
            acc[0][0] += hh0 * w4.x; acc[0][1] += hh0 * w4.y; acc[0][2] += hh0 * w4.z; acc[0][3] += hh0 * w4.w;
            acc[1][0] += hh1 * w4.x; acc[1][1] += hh1 * w4.y; acc[1][2] += hh1 * w4.z; acc[1][3] += hh1 * w4.w;
            acc[2][0] += hh2 * w4.x; acc[2][1] += hh2 * w4.y; acc[2][2] += hh2 * w4.z; acc[2][3] += hh2 * w4.w;
            acc[3][0] += hh3 * w4.x; acc[3][1] += hh3 * w4.y; acc[3][2] += hh3 * w4.z; acc[3][3] += hh3 * w4.w;
        }
    }
    float b0 = bias[cg], b1 = bias[cg + 1], b2 = bias[cg + 2], b3 = bias[cg + 3];
    #pragma unroll
    for (int i = 0; i < 4; i++) {
        acc[i][0] += b0; acc[i][1] += b1; acc[i][2] += b2; acc[i][3] += b3;
    }
    #pragma unroll
    for (int i = 0; i < 4; i++) {
        int row = row0 + rg + i;
        if (row < n_nodes)
            *(float4*)(hp + (size_t)row * 128 + cg) =
                make_float4(acc[i][0], acc[i][1], acc[i][2], acc[i][3]);
    }
    const int head = cg >> 5;
    float as0 = a_src[cg], as1 = a_src[cg + 1], as2 = a_src[cg + 2], as3 = a_src[cg + 3];
    float at0 = a_tgt[cg], at1 = a_tgt[cg + 1], at2 = a_tgt[cg + 2], at3 = a_tgt[cg + 3];
    float p1[4], p2[4];
    #pragma unroll
    for (int i = 0; i < 4; i++) {
        p1[i] = acc[i][0] * as0 + acc[i][1] * as1 + acc[i][2] * as2 + acc[i][3] * as3;
        p2[i] = acc[i][0] * at0 + acc[i][1] * at1 + acc[i][2] * at2 + acc[i][3] * at3;
    }
    #pragma unroll
    for (int m = 1; m < 8; m <<= 1) {
        #pragma unroll
        for (int i = 0; i < 4; i++) {
            p1[i] += __shfl_xor(p1[i], m);
            p2[i] += __shfl_xor(p2[i], m);
        }
    }
    if ((t & 7) == 0) {
        #pragma unroll
        for (int i = 0; i < 4; i++) { sh_s[rg + i][head] = p1[i]; sh_t[rg + i][head] = p2[i]; }
    }
    __syncthreads();
    if (t < 128) {
        int r = t >> 2, h = t & 3;
        int row = row0 + r;
        if (row < n_nodes) ssrc[(size_t)row * 4 + h] = sh_s[r][h];
    } else {
        int r = (t - 128) >> 2, h = t & 3;
        int row = row0 + r;
        if (row < n_nodes) stgt[(size_t)row * 4 + h] = sh_t[r][h];
    }
}

// ---------------------------------------------------------------------------
// Histogram + rank: rank[e] = arrival index of edge e at its target.
// ---------------------------------------------------------------------------
__global__ __launch_bounds__(256) void k_hist(
    const void* __restrict__ eidx, const int* __restrict__ flags,
    int* __restrict__ cnt, int* __restrict__ rank, int n_edges, int n_nodes)
{
    int e = blockIdx.x * 256 + threadIdx.x;
    if (e >= n_edges) return;
    int t = get_i(eidx, (size_t)n_edges + e, flags[1]);
    t = min(max(t, 0), n_nodes - 1);
    rank[e] = atomicAdd(&cnt[t], 1);
}

// ---------------------------------------------------------------------------
// Scan phase 1: per-block exclusive scan + block sums.
// ---------------------------------------------------------------------------
__global__ __launch_bounds__(256) void k_scan1(
    const int* __restrict__ cnt, int* __restrict__ offs, int* __restrict__ bsum, int n)
{
    __shared__ int lds[256];
    const int t = threadIdx.x;
    const int idx = blockIdx.x * 1024 + t * 4;
    int v[4];
    #pragma unroll
    for (int j = 0; j < 4; j++) v[j] = (idx + j < n) ? cnt[idx + j] : 0;
    int s = v[0] + v[1] + v[2] + v[3];
    lds[t] = s;
    __syncthreads();
    #pragma unroll
    for (int off = 1; off < 256; off <<= 1) {
        int x = (t >= off) ? lds[t - off] : 0;
        __syncthreads();
        lds[t] += x;
        __syncthreads();
    }
    int run = lds[t] - s;
    #pragma unroll
    for (int j = 0; j < 4; j++) {
        if (idx + j < n) offs[idx + j] = run;
        run += v[j];
    }
    if (t == 255) bsum[blockIdx.x] = lds[255];
}

// ---------------------------------------------------------------------------
// Scan phase 2 (fused): each block redundantly scans bsum (nb<=256) in LDS,
// then adds its exclusive prefix to its offs chunk.
// ---------------------------------------------------------------------------
__global__ __launch_bounds__(256) void k_scan3(
    int* __restrict__ offs, const int* __restrict__ bsum, int n, int n_edges, int nb)
{
    __shared__ int lds[256];
    __shared__ int excl[256];
    const int t = threadIdx.x;
    int v = (t < nb) ? bsum[t] : 0;
    lds[t] = v;
    __syncthreads();
    #pragma unroll
    for (int off = 1; off < 256; off <<= 1) {
        int x = (t >= off) ? lds[t - off] : 0;
        __syncthreads();
        lds[t] += x;
        __syncthreads();
    }
    excl[t] = lds[t] - v;
    __syncthreads();
    const int add = excl[blockIdx.x];
    const int idx = blockIdx.x * 1024 + t * 4;
    #pragma unroll
    for (int j = 0; j < 4; j++)
        if (idx + j < n) offs[idx + j] += add;
    if (blockIdx.x == 0 && t == 0) offs[n] = n_edges;
}

// ---------------------------------------------------------------------------
// Scatter (no atomics): pos = offs[t] + rank[e].
// ---------------------------------------------------------------------------
__global__ __launch_bounds__(256) void k_scatter(
    const void* __restrict__ eidx, const int* __restrict__ flags,
    const int* __restrict__ offs, const int* __restrict__ rank,
    int* __restrict__ src_sorted, int n_edges, int n_nodes)
{
    int e = blockIdx.x * 256 + threadIdx.x;
    if (e >= n_edges) return;
    const int m64 = flags[1];
    int s = get_i(eidx, e, m64);
    int t = get_i(eidx, (size_t)n_edges + e, m64);
    s = min(max(s, 0), n_nodes - 1);
    t = min(max(t, 0), n_nodes - 1);
    src_sorted[offs[t] + rank[e]] = s;
}

// ---------------------------------------------------------------------------
// Aggregation: wave per target.
// bf16 path rewritten round-0: degrees are Poisson(16) (deg<=64 essentially
// always), so:
//   phase 1: ONE coalesced load of all <=64 src indices (lane = edge), ONE
//            ssrc gather + exp per edge (was 16x redundant per edge), denom
//            from a register shuffle tree instead of per-edge accumulation.
//   phase 2: 16 statically-unrolled 4-edge row-gather slots, indices/weights
//            delivered by __shfl (register-only, no dependent index loads),
//            depth-8 load pipeline -> uniform MLP regardless of degree (the
//            old tail loop serialized: 1 load in flight per 4 edges, and 47%
//            of nodes never reached the x16 main loop).
// deg>64 falls back to the old gather loop (never taken for Poisson(16)).
// ---------------------------------------------------------------------------
__global__ __launch_bounds__(256) void k_agg_csr(
    const int* __restrict__ offs, const int* __restrict__ src_sorted,
    const float* __restrict__ ssrc, const float* __restrict__ stgt,
    const void* __restrict__ hp, void* __restrict__ out,
    const int* __restrict__ flags, int n_nodes)
{
    __shared__ u16 ob[4][128];
    const int wave = threadIdx.x >> 6;
    int wid = (blockIdx.x * 256 + threadIdx.x) >> 6;
    if (wid >= n_nodes) return;
    const int lane = threadIdx.x & 63;
    const int fp32 = flags[0];
    const int d0 = offs[wid], d1 = offs[wid + 1];

    if (!fp32) {
        const int sub = lane >> 4;    // edge slot 0..3 within a 4-edge group
        const int li = lane & 15;     // uint4 of 8 permuted feats
        const u16* hpb = (const u16*)hp;
        const float4* ssrc4 = (const float4*)ssrc;
        const float4 st4 = ((const float4*)stgt)[wid];
        const int deg = d1 - d0;

        float a[8] = {};
        auto accum = [&](float4 w, uint4 v) {
            a[0] += w.x * bf2f((u16)(v.x & 0xffff));
            a[1] += w.x * bf2f((u16)(v.x >> 16));
            a[2] += w.y * bf2f((u16)(v.y & 0xffff));
            a[3] += w.y * bf2f((u16)(v.y >> 16));
            a[4] += w.z * bf2f((u16)(v.z & 0xffff));
            a[5] += w.z * bf2f((u16)(v.z >> 16));
            a[6] += w.w * bf2f((u16)(v.w & 0xffff));
            a[7] += w.w * bf2f((u16)(v.w >> 16));
        };

        // ---- phase 1: lane = edge; index + weight for first min(deg,64) edges
        const int nh = min(deg, 64);
        int my_s = 0;
        float4 my_w = make_float4(0.f, 0.f, 0.f, 0.f);
        if (nh > 0) {
            my_s = src_sorted[d0 + min(lane, nh - 1)];   // one coalesced load
            float4 cs = ssrc4[my_s];
            if (lane < nh) {
                my_w = make_float4(__expf(lrelu_clamp(cs.x + st4.x)),
                                   __expf(lrelu_clamp(cs.y + st4.y)),
                                   __expf(lrelu_clamp(cs.z + st4.z)),
                                   __expf(lrelu_clamp(cs.w + st4.w)));
            }
        }

        // ---- phase 2: statically-pipelined row gather, 4 edges per slot
        const int ns = (nh + 3) >> 2;          // 0..16 slots (wave-uniform)
        auto sload = [&](int k, uint4& vv) {
            if (k < ns) {
                int s = __shfl(my_s, k * 4 + sub);
                vv = *(const uint4*)(hpb + (size_t)s * 128 + li * 8);
            }
        };
        auto sacc = [&](int k, uint4 vv) {
            if (k < ns) {
                int idx = k * 4 + sub;
                float4 w;
                w.x = __shfl(my_w.x, idx);
                w.y = __shfl(my_w.y, idx);
                w.z = __shfl(my_w.z, idx);
                w.w = __shfl(my_w.w, idx);
                accum(w, vv);
            }
        };
        uint4 v0{}, v1{}, v2{}, v3{}, v4{}, v5{}, v6{}, v7{};
        sload(0, v0); sload(1, v1); sload(2, v2); sload(3, v3);
        sload(4, v4); sload(5, v5); sload(6, v6); sload(7, v7);
        sacc(0, v0); sload(8, v0);
        sacc(1, v1); sload(9, v1);
        sacc(2, v2); sload(10, v2);
        sacc(3, v3); sload(11, v3);
        sacc(4, v4); sload(12, v4);
        sacc(5, v5); sload(13, v5);
        sacc(6, v6); sload(14, v6);
        sacc(7, v7); sload(15, v7);
        sacc(8, v0); sacc(9, v1); sacc(10, v2); sacc(11, v3);
        sacc(12, v4); sacc(13, v5); sacc(14, v6); sacc(15, v7);

        // ---- tail (deg > 64): old-style per-group gather; ~never taken
        float4 es_t = make_float4(0.f, 0.f, 0.f, 0.f);
        if (deg > 64) {
            for (int e = d0 + 64; e < d1; e += 4) {
                int idx = e + sub;
                int ok = idx < d1;
                int s = src_sorted[ok ? idx : d1 - 1];
                uint4 v = *(const uint4*)(hpb + (size_t)s * 128 + li * 8);
                float4 cs = ssrc4[s];
                float4 w = make_float4(__expf(lrelu_clamp(cs.x + st4.x)),
                                       __expf(lrelu_clamp(cs.y + st4.y)),
                                       __expf(lrelu_clamp(cs.z + st4.z)),
                                       __expf(lrelu_clamp(cs.w + st4.w)));
                if (!ok) w = make_float4(0.f, 0.f, 0.f, 0.f);
                accum(w, v);
                es_t.x += w.x; es_t.y += w.y; es_t.z += w.z; es_t.w += w.w;
            }
        }

        // ---- denominator: reduce head weights within 16-lane groups first
        float4 es = my_w;
        #pragma unroll
        for (int m = 1; m < 16; m <<= 1) {
            es.x += __shfl_xor(es.x, m);
            es.y += __shfl_xor(es.y, m);
            es.z += __shfl_xor(es.z, m);
            es.w += __shfl_xor(es.w, m);
        }
        // tail es is subgroup-uniform (same value in all 16 lanes of a slot)
        es.x += es_t.x; es.y += es_t.y; es.z += es_t.z; es.w += es_t.w;

        // ---- combine 4 edge slots (xor over lane bits 4,5 keeps li fixed)
        #pragma unroll
        for (int m = 0; m < 8; m++) {
            a[m] += __shfl_xor(a[m], 16);
            a[m] += __shfl_xor(a[m], 32);
        }
        es.x += __shfl_xor(es.x, 16); es.x += __shfl_xor(es.x, 32);
        es.y += __shfl_xor(es.y, 16); es.y += __shfl_xor(es.y, 32);
        es.z += __shfl_xor(es.z, 16); es.z += __shfl_xor(es.z, 32);
        es.w += __shfl_xor(es.w, 16); es.w += __shfl_xor(es.w, 32);

        if (sub == 0) {
            float inv[4] = {1.f / (es.x + 1e-16f), 1.f / (es.y + 1e-16f),
                            1.f / (es.z + 1e-16f), 1.f / (es.w + 1e-16f)};
            #pragma unroll
            for (int m = 0; m < 8; m++)
                ob[wave][m * 16 + li] = f2bf(a[m] * inv[m >> 1]);   // c = m*16+li
            uint4 ov = *(const uint4*)&ob[wave][li * 8];            // un-permuted 16B
            *(uint4*)((u16*)out + (size_t)wid * 128 + li * 8) = ov;
        }
    } else {
        // fp32 fallback: 2 edge slots x 32 lanes x float4, hp un-permuted.
        const int sub = lane >> 5;
        const int li = lane & 31;
        const int head = li >> 3;
        const float* hpf = (const float*)hp;
        const float st = stgt[(size_t)wid * 4 + head];
        float a0 = 0.f, a1 = 0.f, a2 = 0.f, a3 = 0.f, es = 0.f;
        for (int e = d0; e < d1; e += 2) {
            int idx = e + sub;
            int ok = idx < d1;
            int s = src_sorted[ok ? idx : d1 - 1];
            float c = ssrc[(size_t)s * 4 + head];
            float4 v = *(const float4*)(hpf + (size_t)s * 128 + li * 4);
            float w = ok ? __expf(lrelu_clamp(c + st)) : 0.f;
            a0 += w * v.x; a1 += w * v.y; a2 += w * v.z; a3 += w * v.w;
            es += w;
        }
        a0 += __shfl_xor(a0, 32); a1 += __shfl_xor(a1, 32);
        a2 += __shfl_xor(a2, 32); a3 += __shfl_xor(a3, 32);
        es += __shfl_xor(es, 32);
        float inv = 1.0f / (es + 1e-16f);
        if (sub == 0) {
            *(float4*)((float*)out + (size_t)wid * 128 + li * 4) =
                make_float4(a0 * inv, a1 * inv, a2 * inv, a3 * inv);
        }
    }
}

extern "C" void kernel_launch(void* const* d_in, const int* in_sizes, int n_in,
                              void* d_out, int out_size, void* d_ws, size_t ws_size,
                              hipStream_t stream)
{
    const void* h_in  = d_in[0];
    const void* eidx  = d_in[1];
    const void* W     = d_in[2];
    const void* bias  = d_in[3];
    const void* a_src = d_in[4];
    const void* a_tgt = d_in[5];

    const int n_nodes = in_sizes[0] / 128;
    const int n_edges = in_sizes[1] / 2;
    const int nb = (n_nodes + 1023) / 1024;   // <= 256

    char* p = (char*)d_ws;
    auto alloc = [&](size_t bytes) { char* q = p; p += (bytes + 255) & ~(size_t)255; return q; };
    int*   flags      = (int*)  alloc(256);
    void*  hp         = (void*) alloc((size_t)n_nodes * 128 * sizeof(float)); // fp32 worst case
    u16*   Wt         = (u16*)  alloc(128 * 128 * sizeof(u16));
    float* ssrc       = (float*)alloc((size_t)n_nodes * 4 * sizeof(float));
    float* stgt       = (float*)alloc((size_t)n_nodes * 4 * sizeof(float));
    int*   cnt        = (int*)  alloc((size_t)n_nodes * sizeof(int));
    int*   offs       = (int*)  alloc(((size_t)n_nodes + 1) * sizeof(int));
    int*   bsum       = (int*)  alloc(256 * sizeof(int));
    int*   rank       = (int*)  alloc((size_t)n_edges * sizeof(int));
    int*   src_sorted = (int*)  alloc((size_t)n_edges * sizeof(int));

    k_init     <<<65, 256, 0, stream>>>((const u16*)h_in, (const int*)eidx, flags,
                                        (const u16*)W, Wt, cnt, n_nodes);
    k_proj_mfma<<<(n_nodes + 63) / 64, 256, 0, stream>>>((const u16*)h_in, Wt, (const u16*)bias,
                                                         (const u16*)a_src, (const u16*)a_tgt,
                                                         flags, (u16*)hp, ssrc, stgt, n_nodes);
    k_proj_f32 <<<(n_nodes + 31) / 32, 256, 0, stream>>>((const float*)h_in, (const float*)W,
                                                         (const float*)bias, (const float*)a_src,
                                                         (const float*)a_tgt, flags, (float*)hp,
                                                         ssrc, stgt, n_nodes);
    k_hist     <<<(n_edges + 255) / 256, 256, 0, stream>>>(eidx, flags, cnt, rank, n_edges, n_nodes);
    k_scan1    <<<nb, 256, 0, stream>>>(cnt, offs, bsum, n_nodes);
    k_scan3    <<<nb, 256, 0, stream>>>(offs, bsum, n_nodes, n_edges, nb);
    k_scatter  <<<(n_edges + 255) / 256, 256, 0, stream>>>(eidx, flags, offs, rank,
                                                           src_sorted, n_edges, n_nodes);
    k_agg_csr  <<<(n_nodes + 3) / 4, 256, 0, stream>>>(offs, src_sorted, ssrc, stgt,
                                                       hp, d_out, flags, n_nodes);
}